// Round 1
// baseline (799.737 us; speedup 1.0000x reference)
//
#include <hip/hip_runtime.h>

#define NN 100000
#define NE 3200000
#define HID 32
#define NBLK ((NN + 255) / 256)

// ---------------- CSR build ----------------

__global__ __launch_bounds__(256) void k_hist(const int* __restrict__ recv, int* __restrict__ cnt) {
  int stride = gridDim.x * blockDim.x;
  for (int i = blockIdx.x * blockDim.x + threadIdx.x; i < NE; i += stride)
    atomicAdd(&cnt[recv[i]], 1);
}

__global__ __launch_bounds__(256) void k_scan1(const int* __restrict__ cnt, int* __restrict__ bsum) {
  __shared__ int s[256];
  int n = blockIdx.x * 256 + threadIdx.x;
  s[threadIdx.x] = (n < NN) ? cnt[n] : 0;
  __syncthreads();
  for (int o = 128; o > 0; o >>= 1) {
    if (threadIdx.x < o) s[threadIdx.x] += s[threadIdx.x + o];
    __syncthreads();
  }
  if (threadIdx.x == 0) bsum[blockIdx.x] = s[0];
}

__global__ __launch_bounds__(512) void k_scan2(int* __restrict__ bsum, int nb) {
  __shared__ int s[512];
  int t = threadIdx.x;
  int v = (t < nb) ? bsum[t] : 0;
  s[t] = v;
  __syncthreads();
  for (int o = 1; o < 512; o <<= 1) {
    int x = (t >= o) ? s[t - o] : 0;
    __syncthreads();
    s[t] += x;
    __syncthreads();
  }
  if (t < nb) bsum[t] = s[t] - v;  // exclusive scan of block sums
}

__global__ __launch_bounds__(256) void k_scan3(const int* __restrict__ cnt, const int* __restrict__ bsum,
                                               int* __restrict__ row_off, int* __restrict__ cursor) {
  __shared__ int s[256];
  int t = threadIdx.x;
  int n = blockIdx.x * 256 + t;
  int c = (n < NN) ? cnt[n] : 0;
  s[t] = c;
  __syncthreads();
  for (int o = 1; o < 256; o <<= 1) {
    int x = (t >= o) ? s[t - o] : 0;
    __syncthreads();
    s[t] += x;
    __syncthreads();
  }
  if (n < NN) {
    int off = s[t] - c + bsum[blockIdx.x];
    row_off[n] = off;
    cursor[n] = off;
    if (n == NN - 1) row_off[NN] = off + c;
  }
}

__global__ __launch_bounds__(256) void k_scatter(const int* __restrict__ send, const int* __restrict__ recv,
                                                 const float* __restrict__ ef, const float* __restrict__ mask,
                                                 int* __restrict__ cursor, float4* __restrict__ sorted) {
  int stride = gridDim.x * blockDim.x;
  for (int i = blockIdx.x * blockDim.x + threadIdx.x; i < NE; i += stride) {
    int r = recv[i];
    int pos = atomicAdd(&cursor[r], 1);
    float4 v;
    v.x = __int_as_float(send[i]);
    v.y = ef[2 * i];
    v.z = ef[2 * i + 1];
    v.w = mask[i];
    sorted[pos] = v;
  }
}

// ---------------- init: h = PQ@W_in + b_in ; Vp=(1,0); a,b projections for layer 0 ----------------

__global__ __launch_bounds__(256) void k_init(const float* __restrict__ PQ,
                                              const float* __restrict__ Win, const float* __restrict__ bin,
                                              const float* __restrict__ Wm, const float* __restrict__ bm,
                                              float* __restrict__ h, float* __restrict__ a,
                                              float* __restrict__ bp, float* __restrict__ Vp) {
  __shared__ float sW[70 * 32];
  __shared__ float sWin[64];
  __shared__ float sbin[32];
  __shared__ float sbm[32];
  for (int i = threadIdx.x; i < 70 * 32; i += blockDim.x) sW[i] = Wm[i];
  for (int i = threadIdx.x; i < 64; i += blockDim.x) sWin[i] = Win[i];
  for (int i = threadIdx.x; i < 32; i += blockDim.x) { sbin[i] = bin[i]; sbm[i] = bm[i]; }
  __syncthreads();
  int n = blockIdx.x * blockDim.x + threadIdx.x;
  if (n >= NN) return;
  float p0 = PQ[2 * n], p1 = PQ[2 * n + 1];
  float hh[32];
#pragma unroll
  for (int j = 0; j < 32; j++) hh[j] = fmaf(p0, sWin[j], fmaf(p1, sWin[32 + j], sbin[j]));
  float4* h4 = (float4*)(h + n * 32);
#pragma unroll
  for (int j = 0; j < 8; j++) h4[j] = make_float4(hh[4*j], hh[4*j+1], hh[4*j+2], hh[4*j+3]);
  Vp[2 * n] = 1.0f;
  Vp[2 * n + 1] = 0.0f;
  // a[j] = Wm[0][j]*1 + Wm[1][j]*0 + sum_k hh[k]*Wm[2+k][j]
  // b[j] = Wm[34][j]*1 + Wm[35][j]*0 + sum_k hh[k]*Wm[36+k][j] + bm[j]
  float av[32], bv[32];
#pragma unroll
  for (int j = 0; j < 32; j++) { av[j] = sW[j]; bv[j] = sW[34 * 32 + j] + sbm[j]; }
  for (int k = 0; k < 32; k++) {
    float hk = hh[k];
#pragma unroll
    for (int j = 0; j < 32; j++) {
      av[j] = fmaf(hk, sW[(2 + k) * 32 + j], av[j]);
      bv[j] = fmaf(hk, sW[(36 + k) * 32 + j], bv[j]);
    }
  }
  float4* a4 = (float4*)(a + n * 32);
  float4* b4 = (float4*)(bp + n * 32);
#pragma unroll
  for (int j = 0; j < 8; j++) {
    a4[j] = make_float4(av[4*j], av[4*j+1], av[4*j+2], av[4*j+3]);
    b4[j] = make_float4(bv[4*j], bv[4*j+1], bv[4*j+2], bv[4*j+3]);
  }
}

// ---------------- per-layer edge aggregation (CSR gather, no atomics) ----------------

__global__ __launch_bounds__(256) void k_edge(const float* __restrict__ a, const float* __restrict__ bp,
                                              const int* __restrict__ row_off, const float4* __restrict__ sorted,
                                              const float* __restrict__ Wm, float* __restrict__ agg) {
  __shared__ float sWe[64];  // rows 68,69 of W_msg
  if (threadIdx.x < 64) sWe[threadIdx.x] = Wm[68 * 32 + threadIdx.x];
  __syncthreads();
  int n = blockIdx.x * blockDim.x + threadIdx.x;
  if (n >= NN) return;
  float bn[32], acc[32];
  const float4* bp4 = (const float4*)(bp + n * 32);
#pragma unroll
  for (int j = 0; j < 8; j++) {
    float4 v = bp4[j];
    bn[4*j] = v.x; bn[4*j+1] = v.y; bn[4*j+2] = v.z; bn[4*j+3] = v.w;
  }
#pragma unroll
  for (int j = 0; j < 32; j++) acc[j] = 0.0f;
  int e0 = row_off[n], e1 = row_off[n + 1];
  for (int e = e0; e < e1; e++) {
    float4 ed = sorted[e];
    int s = __float_as_int(ed.x);
    float c0 = ed.y, c1 = ed.z, mk = ed.w;
    const float4* a4 = (const float4*)(a + s * 32);
#pragma unroll
    for (int j = 0; j < 8; j++) {
      float4 av = a4[j];
      float t0 = fmaf(c0, sWe[4*j+0], fmaf(c1, sWe[32+4*j+0], bn[4*j+0]));
      float t1 = fmaf(c0, sWe[4*j+1], fmaf(c1, sWe[32+4*j+1], bn[4*j+1]));
      float t2 = fmaf(c0, sWe[4*j+2], fmaf(c1, sWe[32+4*j+2], bn[4*j+2]));
      float t3 = fmaf(c0, sWe[4*j+3], fmaf(c1, sWe[32+4*j+3], bn[4*j+3]));
      acc[4*j+0] = fmaf(fmaxf(av.x + t0, 0.0f), mk, acc[4*j+0]);
      acc[4*j+1] = fmaf(fmaxf(av.y + t1, 0.0f), mk, acc[4*j+1]);
      acc[4*j+2] = fmaf(fmaxf(av.z + t2, 0.0f), mk, acc[4*j+2]);
      acc[4*j+3] = fmaf(fmaxf(av.w + t3, 0.0f), mk, acc[4*j+3]);
    }
  }
  float4* agg4 = (float4*)(agg + n * 32);
#pragma unroll
  for (int j = 0; j < 8; j++) agg4[j] = make_float4(acc[4*j], acc[4*j+1], acc[4*j+2], acc[4*j+3]);
}

// ---------------- per-layer node update (+ next-layer projections fused) ----------------

__global__ __launch_bounds__(256) void k_node(const float* __restrict__ agg,
                                              const float* __restrict__ Wu, const float* __restrict__ bu,
                                              const float* __restrict__ Wd, const float* __restrict__ bd,
                                              const float* __restrict__ Wm, const float* __restrict__ bm,
                                              float* __restrict__ h, float* __restrict__ a,
                                              float* __restrict__ bp, float* __restrict__ Vp,
                                              float* __restrict__ out, int last) {
  __shared__ float sWu[66 * 32];
  __shared__ float sWm[70 * 32];
  __shared__ float sbu[32];
  __shared__ float sWd[64];
  __shared__ float sbd[2];
  __shared__ float sbm[32];
  for (int i = threadIdx.x; i < 66 * 32; i += blockDim.x) sWu[i] = Wu[i];
  for (int i = threadIdx.x; i < 70 * 32; i += blockDim.x) sWm[i] = Wm[i];
  for (int i = threadIdx.x; i < 32; i += blockDim.x) { sbu[i] = bu[i]; sbm[i] = bm[i]; }
  for (int i = threadIdx.x; i < 64; i += blockDim.x) sWd[i] = Wd[i];
  if (threadIdx.x < 2) sbd[threadIdx.x] = bd[threadIdx.x];
  __syncthreads();
  int n = blockIdx.x * blockDim.x + threadIdx.x;
  if (n >= NN) return;
  float v0 = Vp[2 * n], v1 = Vp[2 * n + 1];
  float hh[32], ag[32];
  const float4* h4 = (const float4*)(h + n * 32);
  const float4* g4 = (const float4*)(agg + n * 32);
#pragma unroll
  for (int j = 0; j < 8; j++) {
    float4 x = h4[j];
    hh[4*j] = x.x; hh[4*j+1] = x.y; hh[4*j+2] = x.z; hh[4*j+3] = x.w;
    float4 y = g4[j];
    ag[4*j] = y.x; ag[4*j+1] = y.y; ag[4*j+2] = y.z; ag[4*j+3] = y.w;
  }
  // v_out = [Vp, h, agg] @ W_upd + b_upd  (rows: 0..1 Vp, 2..33 h, 34..65 agg)
  float vo[32];
#pragma unroll
  for (int j = 0; j < 32; j++) vo[j] = fmaf(v0, sWu[j], fmaf(v1, sWu[32 + j], sbu[j]));
  for (int k = 0; k < 32; k++) {
    float hk = hh[k], ak = ag[k];
#pragma unroll
    for (int j = 0; j < 32; j++) {
      vo[j] = fmaf(hk, sWu[(2 + k) * 32 + j], vo[j]);
      vo[j] = fmaf(ak, sWu[(34 + k) * 32 + j], vo[j]);
    }
  }
#pragma unroll
  for (int j = 0; j < 32; j++) hh[j] = fmaxf(vo[j], 0.0f);  // h = relu(v_out)
  // delta_V = h @ W_delta + b_delta ; Vp += delta
  float d0 = sbd[0], d1 = sbd[1];
  for (int k = 0; k < 32; k++) {
    d0 = fmaf(hh[k], sWd[2 * k], d0);
    d1 = fmaf(hh[k], sWd[2 * k + 1], d1);
  }
  v0 += d0;
  v1 += d1;
  if (last) {
    out[2 * n] = v0;
    out[2 * n + 1] = v1;
    return;
  }
  Vp[2 * n] = v0;
  Vp[2 * n + 1] = v1;
  float4* hw4 = (float4*)(h + n * 32);
#pragma unroll
  for (int j = 0; j < 8; j++) hw4[j] = make_float4(hh[4*j], hh[4*j+1], hh[4*j+2], hh[4*j+3]);
  // next-layer projections
  float av[32], bv[32];
#pragma unroll
  for (int j = 0; j < 32; j++) {
    av[j] = fmaf(v0, sWm[j], v1 * sWm[32 + j]);
    bv[j] = fmaf(v0, sWm[34 * 32 + j], fmaf(v1, sWm[35 * 32 + j], sbm[j]));
  }
  for (int k = 0; k < 32; k++) {
    float hk = hh[k];
#pragma unroll
    for (int j = 0; j < 32; j++) {
      av[j] = fmaf(hk, sWm[(2 + k) * 32 + j], av[j]);
      bv[j] = fmaf(hk, sWm[(36 + k) * 32 + j], bv[j]);
    }
  }
  float4* a4 = (float4*)(a + n * 32);
  float4* b4 = (float4*)(bp + n * 32);
#pragma unroll
  for (int j = 0; j < 8; j++) {
    a4[j] = make_float4(av[4*j], av[4*j+1], av[4*j+2], av[4*j+3]);
    b4[j] = make_float4(bv[4*j], bv[4*j+1], bv[4*j+2], bv[4*j+3]);
  }
}

// ---------------- launch ----------------

extern "C" void kernel_launch(void* const* d_in, const int* in_sizes, int n_in,
                              void* d_out, int out_size, void* d_ws, size_t ws_size,
                              hipStream_t stream) {
  const float* PQ   = (const float*)d_in[0];
  const int*   send = (const int*)d_in[1];
  const int*   recv = (const int*)d_in[2];
  const float* ef   = (const float*)d_in[3];
  const float* mask = (const float*)d_in[4];
  const float* Win  = (const float*)d_in[5];
  const float* bin  = (const float*)d_in[6];
  const float* Wmsg = (const float*)d_in[7];   // [3,70,32]
  const float* bmsg = (const float*)d_in[8];   // [3,32]
  const float* Wupd = (const float*)d_in[9];   // [3,66,32]
  const float* bupd = (const float*)d_in[10];  // [3,32]
  const float* Wdel = (const float*)d_in[11];  // [3,32,2]
  const float* bdel = (const float*)d_in[12];  // [3,2]
  float* out = (float*)d_out;

  char* w = (char*)d_ws;
  auto alloc = [&](size_t bytes) {
    char* p = w;
    w += (bytes + 255) & ~(size_t)255;
    return p;
  };
  float4* sorted = (float4*)alloc((size_t)NE * 16);
  int* cnt     = (int*)alloc((size_t)NN * 4);
  int* row_off = (int*)alloc(((size_t)NN + 1) * 4);
  int* cursor  = (int*)alloc((size_t)NN * 4);
  int* bsum    = (int*)alloc(512 * 4);
  float* h   = (float*)alloc((size_t)NN * 32 * 4);
  float* a   = (float*)alloc((size_t)NN * 32 * 4);
  float* bp  = (float*)alloc((size_t)NN * 32 * 4);
  float* agg = (float*)alloc((size_t)NN * 32 * 4);
  float* Vp  = (float*)alloc((size_t)NN * 2 * 4);

  hipMemsetAsync(cnt, 0, (size_t)NN * 4, stream);
  k_hist<<<2048, 256, 0, stream>>>(recv, cnt);
  k_scan1<<<NBLK, 256, 0, stream>>>(cnt, bsum);
  k_scan2<<<1, 512, 0, stream>>>(bsum, NBLK);
  k_scan3<<<NBLK, 256, 0, stream>>>(cnt, bsum, row_off, cursor);
  k_scatter<<<2048, 256, 0, stream>>>(send, recv, ef, mask, cursor, sorted);

  k_init<<<NBLK, 256, 0, stream>>>(PQ, Win, bin, Wmsg, bmsg, h, a, bp, Vp);

  for (int l = 0; l < 3; l++) {
    int last = (l == 2) ? 1 : 0;
    int lnext = (l + 1) % 3;  // dummy (layer 0) weights when last
    k_edge<<<NBLK, 256, 0, stream>>>(a, bp, row_off, sorted, Wmsg + l * 70 * 32, agg);
    k_node<<<NBLK, 256, 0, stream>>>(agg, Wupd + l * 66 * 32, bupd + l * 32,
                                     Wdel + l * 64, bdel + l * 2,
                                     Wmsg + lnext * 70 * 32, bmsg + lnext * 32,
                                     h, a, bp, Vp, out, last);
  }
}